// Round 13
// baseline (293.751 us; speedup 1.0000x reference)
//
#include <hip/hip_runtime.h>
#include <hip/hip_bf16.h>
#include <stdint.h>

// ElementReadoutMLP: species-routed 2-layer MLP, fused.
// r13 design: WAVE-AUTONOMOUS gemm (no per-tile barriers -- r4..r12 all
// plateaued at 50-70us on the barriered tile machine; stall, not pipes).
//   bhist_k / scan_k / dscatter_k : countsort atoms by species;
//     scan_k partitions gemm blocks across species by 32-atom GROUPS.
//   convw_k : W1 -> pre-swizzled bf16 wt (LDS-image layout, coalesced)
//   gemm_k  : 256 blocks x 512 thr, ONE species per block.  Whole W1[e]
//             (128KB bf16) -> LDS once; ONE barrier; then each wave
//             independently processes 32-atom groups: x gathered straight
//             into MFMA fragments (depth-2 pipelined), swapped MFMA
//             D[n][atom] vs LDS-resident W, in-lane SiLU+w2 dot,
//             2 shfl_xor, store.  Zero barriers in the grind loop.

#define NDIM 256
#define CHUNKS 16      // scan chunks per species (NE*CHUNKS <= 256)
#define BCHUNK 16384   // bytes per W k-chunk (256 n x 32 k x 2B)
#define GRP 32         // atoms per group (one wave-iteration)
#define GCH 32         // groups per table refill chunk (1024 atoms)
#define NB_GEMM 256    // persistent gemm grid (1 block/CU)

typedef __attribute__((ext_vector_type(8))) short short8;
typedef __attribute__((ext_vector_type(8))) unsigned short ushort8;
typedef __attribute__((ext_vector_type(4))) float f32x4;

__device__ __forceinline__ unsigned short f2bf(float f) {
  unsigned u = __float_as_uint(f);
  u = (u + 0x7FFFu + ((u >> 16) & 1u)) >> 16;   // round-to-nearest-even
  return (unsigned short)u;
}

// async global->LDS, 16B per lane; lds dest wave-uniform base (+lane*16 HW).
__device__ __forceinline__ void gload_lds16(const void* gsrc, void* ldst) {
  __builtin_amdgcn_global_load_lds(
      (const __attribute__((address_space(1))) unsigned*)gsrc,
      (__attribute__((address_space(3))) unsigned*)(uintptr_t)(unsigned)(uintptr_t)ldst,
      16, 0, 0);
}

// pack 8 fp32 -> short8 of bf16 (RNE, packed cvt)
__device__ __forceinline__ short8 cvt8(float4 lo, float4 hi) {
  union { short8 s; unsigned u[4]; } r;
  __hip_bfloat162 t;
  t = __float22bfloat162_rn(make_float2(lo.x, lo.y)); r.u[0] = *(unsigned*)&t;
  t = __float22bfloat162_rn(make_float2(lo.z, lo.w)); r.u[1] = *(unsigned*)&t;
  t = __float22bfloat162_rn(make_float2(hi.x, hi.y)); r.u[2] = *(unsigned*)&t;
  t = __float22bfloat162_rn(make_float2(hi.z, hi.w)); r.u[3] = *(unsigned*)&t;
  return r.s;
}

// ---- prep kernels -----------------------------------------------------------

// wt layout: chunk(e,step) = wt + (e*8+step)*BCHUNK bytes; within chunk,
// bf16 for (n,kk) at byte ((n*64 + kk*2) ^ ((n&7)<<4)).  Linear copy into
// LDS reproduces the swizzled layout gemm_k's ds_reads expect (rule #21).
__global__ void convw_k(const float* __restrict__ W1, unsigned short* __restrict__ wt, int NE) {
  __shared__ float ldsW[32 * 260];   // 32 k-rows x 256 n, padded
  int blk = blockIdx.x;              // e*8 + step
  int e = blk >> 3, step = blk & 7;
  int tid = threadIdx.x;
  int k0 = step * 32;
  {
    int kk = tid >> 3, part = tid & 7;
    const float* src = W1 + ((size_t)e << 16) + (size_t)(k0 + kk) * NDIM + part * 32;
    #pragma unroll
    for (int j = 0; j < 8; ++j) {
      float4 v = *(const float4*)(src + j * 4);
      *(float4*)&ldsW[kk * 260 + part * 32 + j * 4] = v;
    }
  }
  __syncthreads();
  {
    int n = tid;
    unsigned short v[32];
    #pragma unroll
    for (int kk = 0; kk < 32; ++kk) v[kk] = f2bf(ldsW[kk * 260 + n]);
    char* chunk = (char*)wt + (size_t)blk * BCHUNK;
    unsigned swz = (unsigned)((n & 7) << 4);
    #pragma unroll
    for (int g = 0; g < 4; ++g)
      *(ushort8*)(chunk + (((unsigned)(n * 64 + g * 16)) ^ swz)) = *(ushort8*)&v[g * 8];
  }
}

// per-block histogram, deterministic (ballot-based, no atomics)
__global__ void bhist_k(const int* __restrict__ sp, int n, int* __restrict__ bc, int NE) {
  __shared__ int wc[4][16];
  int tid = threadIdx.x;
  int i = blockIdx.x * 256 + tid;
  int s = (i < n) ? sp[i] : -1;
  int w = tid >> 6, lane = tid & 63;
  for (int e = 0; e < NE; ++e) {
    unsigned long long m = __ballot(s == e);
    if (lane == 0) wc[w][e] = __popcll(m);
  }
  __syncthreads();
  if (tid < NE) bc[blockIdx.x * NE + tid] = wc[0][tid] + wc[1][tid] + wc[2][tid] + wc[3][tid];
}

// deterministic scan: blockCounts -> block offsets, species atom starts,
// species GROUP offsets, and gemm block->species partition.
__global__ void scan_k(const int* __restrict__ bc, int* __restrict__ bo,
                       int* __restrict__ atom_start, int* __restrict__ goff,
                       int* __restrict__ bstart, int nblocks, int NE) {
  __shared__ int csum[256];
  __shared__ int coff[256];
  __shared__ int stot[16];
  __shared__ int sbase[16];
  int tid = threadIdx.x;
  int per = (nblocks + CHUNKS - 1) / CHUNKS;
  int e = tid / CHUNKS, c = tid % CHUNKS;
  int b0 = c * per, b1 = b0 + per; if (b1 > nblocks) b1 = nblocks;
  if (tid < NE * CHUNKS) {
    int s = 0;
    for (int b = b0; b < b1; ++b) s += bc[b * NE + e];
    csum[tid] = s;
  }
  __syncthreads();
  if (tid < NE) {
    int r = 0;
    for (int c2 = 0; c2 < CHUNKS; ++c2) { coff[tid * CHUNKS + c2] = r; r += csum[tid * CHUNKS + c2]; }
    stot[tid] = r;
  }
  __syncthreads();
  if (tid == 0) {
    int a = 0, t = 0;
    for (int e2 = 0; e2 < NE; ++e2) {
      sbase[e2] = a;
      atom_start[e2] = a; goff[e2] = t;
      a += stot[e2]; t += (stot[e2] + GRP - 1) / GRP;
    }
    atom_start[NE] = a; goff[NE] = t;
    // partition NB_GEMM blocks across species proportional to groups, >=1
    int ntl = t > 0 ? t : 1;
    int nbk[16]; int tot = 0, emax = 0;
    for (int e2 = 0; e2 < NE; ++e2) {
      int nt = goff[e2 + 1] - goff[e2];
      int v = (nt > 0) ? (int)(((long long)nt * NB_GEMM) / ntl) : 0;
      if (nt > 0 && v < 1) v = 1;
      nbk[e2] = v; tot += v;
      if (nbk[e2] > nbk[emax]) emax = e2;
    }
    nbk[emax] += NB_GEMM - tot;
    int bacc = 0;
    for (int e2 = 0; e2 < NE; ++e2) { bstart[e2] = bacc; bacc += nbk[e2]; }
    bstart[NE] = bacc;
  }
  __syncthreads();
  if (tid < NE * CHUNKS) {
    int run = sbase[e] + coff[tid];
    for (int b = b0; b < b1; ++b) { bo[b * NE + e] = run; run += bc[b * NE + e]; }
  }
}

// deterministic scatter: rank = block-offset + wave-prefix + lane-prefix
__global__ void dscatter_k(const int* __restrict__ sp, int n, const int* __restrict__ bo,
                           int* __restrict__ sorted, int NE) {
  __shared__ int wc[4][16];
  int tid = threadIdx.x;
  int i = blockIdx.x * 256 + tid;
  int s = (i < n) ? sp[i] : -1;
  int w = tid >> 6, lane = tid & 63;
  for (int e = 0; e < NE; ++e) {
    unsigned long long m = __ballot(s == e);
    if (lane == 0) wc[w][e] = __popcll(m);
  }
  __syncthreads();
  for (int e = 0; e < NE; ++e) {
    unsigned long long m = __ballot(s == e);
    if (s == e) {
      int wpre = 0;
      for (int w2 = 0; w2 < 4; ++w2) if (w2 < w) wpre += wc[w2][e];
      int rank = __popcll(m & ((1ull << lane) - 1ull));
      sorted[bo[blockIdx.x * NE + e] + wpre + rank] = i;
    }
  }
}

// ---- wave-autonomous fused grouped GEMM + SiLU + layer2 ---------------------

__global__ __launch_bounds__(512, 2) void gemm_k(
    const float* __restrict__ x, const unsigned short* __restrict__ wt,
    const float* __restrict__ b1, const float* __restrict__ w2,
    const float* __restrict__ b2, const int* __restrict__ sorted,
    const int* __restrict__ atom_start, const int* __restrict__ goff,
    const int* __restrict__ bstart, float* __restrict__ out, int NE)
{
  // LDS ~138 KB: full W1[e] bf16 (8 chunks x 16KB, swizzled image) +
  // b1/w2 slices + atom table.  1 block/CU, 8 waves, no grind barriers.
  __shared__ __align__(16) char ldsW[8 * BCHUNK];      // 128 KB
  __shared__ __align__(16) float b1s[NDIM], w2s[NDIM];
  __shared__ int ldsAtoms[GCH * GRP];                  // 1024 atoms / chunk
  __shared__ int goffs[17], astart[17], bst[17];

  int tid = threadIdx.x, lane = tid & 63, wid = tid >> 6;   // wid 0..7
  int lr = lane & 15, lg = lane >> 4;

  if (tid <= NE) {
    goffs[tid] = goff[tid]; astart[tid] = atom_start[tid]; bst[tid] = bstart[tid];
  }
  __syncthreads();

  // ---- block -> (species, group range) ----
  int b = blockIdx.x;
  int e = 0;
  while (b >= bst[e + 1]) ++e;
  int j = b - bst[e], nbe = bst[e + 1] - bst[e];
  int nge = goffs[e + 1] - goffs[e];
  int q = nge / nbe, r = nge % nbe;
  int gcnt = q + (j < r ? 1 : 0);
  if (gcnt <= 0) return;
  int g0 = j * q + (j < r ? j : r);          // group index within species
  int rs0 = astart[e] + g0 * GRP;            // first atom (global sorted idx)
  int rvAll = astart[e + 1] - rs0;           // valid atoms in this block

  // ---- W1[e] -> LDS (128 KB, linear copy of pre-swizzled image) ----
  {
    const char* wbase = (const char*)wt + (size_t)e * 8 * BCHUNK;
    #pragma unroll
    for (int i = 0; i < 16; ++i) {
      int off = (wid * 16 + i) * 1024;
      gload_lds16(wbase + off + lane * 16, ldsW + off);
    }
    if (tid < NDIM) {
      b1s[tid] = b1[(size_t)e * NDIM + tid];
      w2s[tid] = w2[(size_t)e * NDIM + tid];
    }
  }
  float b2v = b2[e];

  unsigned aoff = ((unsigned)(lr * 64 + lg * 16)) ^ ((unsigned)((lr & 7) << 4));

  // ---- grind: chunks of GCH groups (table refill); waves independent ----
  for (int gc0 = 0; gc0 < gcnt; gc0 += GCH) {
    int gce = gc0 + GCH < gcnt ? gc0 + GCH : gcnt;
    // refill atom table (clamped -> padded slots duplicate last valid atom)
    __syncthreads();   // prev chunk's readers done (also covers W-load, 1st iter)
    for (int i = tid; i < (gce - gc0) * GRP; i += 512) {
      int aidx = gc0 * GRP + i;
      ldsAtoms[i] = sorted[rs0 + (aidx < rvAll ? aidx : rvAll - 1)];
    }
    __syncthreads();

    for (int g = gc0 + wid; g < gce; g += 8) {
      int tb = (g - gc0) * GRP;
      int a0 = ldsAtoms[tb + lr];
      int a1 = ldsAtoms[tb + 16 + lr];
      const float* xp0 = x + (size_t)a0 * NDIM + lg * 8;
      const float* xp1 = x + (size_t)a1 * NDIM + lg * 8;

      // depth-2 pipelined x gather: cb[3][4] rotating (static idx via unroll)
      float4 cb[3][4];
      #pragma unroll
      for (int s = 0; s < 2; ++s) {
        cb[s][0] = *(const float4*)(xp0 + s * 32);
        cb[s][1] = *(const float4*)(xp0 + s * 32 + 4);
        cb[s][2] = *(const float4*)(xp1 + s * 32);
        cb[s][3] = *(const float4*)(xp1 + s * 32 + 4);
      }

      f32x4 acc[16][2];
      const f32x4 zero = {0.f, 0.f, 0.f, 0.f};
      #pragma unroll
      for (int nf = 0; nf < 16; ++nf) { acc[nf][0] = zero; acc[nf][1] = zero; }

      #pragma unroll
      for (int step = 0; step < 8; ++step) {
        const int cur = step % 3;
        short8 af0 = cvt8(cb[cur][0], cb[cur][1]);
        short8 af1 = cvt8(cb[cur][2], cb[cur][3]);
        if (step < 6) {
          const int nxt = (step + 2) % 3;
          cb[nxt][0] = *(const float4*)(xp0 + (step + 2) * 32);
          cb[nxt][1] = *(const float4*)(xp0 + (step + 2) * 32 + 4);
          cb[nxt][2] = *(const float4*)(xp1 + (step + 2) * 32);
          cb[nxt][3] = *(const float4*)(xp1 + (step + 2) * 32 + 4);
        }
        const char* chunk = ldsW + step * BCHUNK;
        #pragma unroll
        for (int nf = 0; nf < 16; ++nf) {
          short8 bf = *(const short8*)(chunk + nf * 1024 + aoff);
          acc[nf][0] = __builtin_amdgcn_mfma_f32_16x16x32_bf16(bf, af0, acc[nf][0], 0, 0, 0);
          acc[nf][1] = __builtin_amdgcn_mfma_f32_16x16x32_bf16(bf, af1, acc[nf][1], 0, 0, 0);
        }
      }

      // epilogue: lane holds D[n = nf*16 + lg*4 + rg][atom = a0/a1 (col lr)]
      float s0 = 0.f, s1 = 0.f;
      #pragma unroll
      for (int nf = 0; nf < 16; ++nf) {
        f32x4 bb = *(const f32x4*)&b1s[nf * 16 + lg * 4];
        f32x4 wv = *(const f32x4*)&w2s[nf * 16 + lg * 4];
        #pragma unroll
        for (int rg = 0; rg < 4; ++rg) {
          float h0 = acc[nf][0][rg] + bb[rg];
          s0 += h0 * __builtin_amdgcn_rcpf(1.f + __expf(-h0)) * wv[rg];
          float h1 = acc[nf][1][rg] + bb[rg];
          s1 += h1 * __builtin_amdgcn_rcpf(1.f + __expf(-h1)) * wv[rg];
        }
      }
      s0 += __shfl_xor(s0, 16, 64); s0 += __shfl_xor(s0, 32, 64);
      s1 += __shfl_xor(s1, 16, 64); s1 += __shfl_xor(s1, 32, 64);
      if (lg == 0)      out[a0] = s0 + b2v;
      else if (lg == 1) out[a1] = s1 + b2v;
    }
  }
}

// ---- launch -----------------------------------------------------------------

extern "C" void kernel_launch(void* const* d_in, const int* in_sizes, int n_in,
                              void* d_out, int out_size, void* d_ws, size_t ws_size,
                              hipStream_t stream) {
  const float* x  = (const float*)d_in[0];
  const int*   sp = (const int*)d_in[1];
  const float* W1 = (const float*)d_in[2];
  const float* b1 = (const float*)d_in[3];
  const float* W2 = (const float*)d_in[4];
  const float* b2 = (const float*)d_in[5];
  float* out = (float*)d_out;

  int n_atoms = in_sizes[0] / NDIM;
  int NE = in_sizes[2] / (NDIM * NDIM);
  int nblocks = (n_atoms + 255) / 256;

  // workspace layout (all 256-aligned); every word read is written this call.
  char* wsb = (char*)d_ws;
  size_t o = 0;
  int* bc = (int*)(wsb + o);         o += ((size_t)nblocks * NE * 4 + 255) & ~(size_t)255;
  int* bo = (int*)(wsb + o);         o += ((size_t)nblocks * NE * 4 + 255) & ~(size_t)255;
  int* atom_start = (int*)(wsb + o); o += 256;
  int* goff       = (int*)(wsb + o); o += 256;
  int* bstart     = (int*)(wsb + o); o += 256;
  int* sorted     = (int*)(wsb + o); o += ((size_t)n_atoms * 4 + 255) & ~(size_t)255;
  unsigned short* wt = (unsigned short*)(wsb + o);   // NE*128KB, 256-aligned

  hipLaunchKernelGGL(convw_k, dim3(NE * 8), dim3(256), 0, stream, W1, wt, NE);
  hipLaunchKernelGGL(bhist_k, dim3(nblocks), dim3(256), 0, stream, sp, n_atoms, bc, NE);
  hipLaunchKernelGGL(scan_k, dim3(1), dim3(256), 0, stream, bc, bo, atom_start, goff,
                     bstart, nblocks, NE);
  hipLaunchKernelGGL(dscatter_k, dim3(nblocks), dim3(256), 0, stream, sp, n_atoms, bo,
                     sorted, NE);

  hipLaunchKernelGGL(gemm_k, dim3(NB_GEMM), dim3(512), 0, stream,
                     x, wt, b1, W2, b2, sorted, atom_start, goff, bstart, out, NE);
}

// Round 14
// 262.202 us; speedup vs baseline: 1.1203x; 1.1203x over previous
//
#include <hip/hip_runtime.h>
#include <hip/hip_bf16.h>
#include <stdint.h>

// ElementReadoutMLP: species-routed 2-layer MLP, fused.
// r14: wave-autonomous gemm (r13 structure) with a SPILL-PROOF register
// schedule.  r13 died on acc[16][2]=128 VGPR -> RA capped at 128 -> 328MB
// scratch traffic (FETCH_SIZE proof).  r14 keeps x-fragments resident
// (64 VGPR, converted once) and loops over n-pairs with only 4 live
// accumulators, folding each into running scalars immediately.
//   bhist_k / scan_k / dscatter_k : countsort atoms by species;
//     scan_k partitions gemm blocks across species by 32-atom GROUPS.
//   convw_k : W1 -> pre-swizzled bf16 wt (LDS-image layout, coalesced)
//   gemm_k  : 256 blocks x 512 thr, ONE species per block.  Whole W1[e]
//             (128KB bf16) -> LDS once; each wave independently grinds
//             32-atom groups: x gathered to reg fragments, swapped MFMA
//             D[n][atom] vs LDS-resident W (bf shared across 2 atom
//             blocks), in-lane SiLU+w2 dot, 2 shfl_xor, store.  Zero
//             barriers in the grind loop.

#define NDIM 256
#define CHUNKS 16      // scan chunks per species (NE*CHUNKS <= 256)
#define BCHUNK 16384   // bytes per W k-chunk (256 n x 32 k x 2B)
#define GRP 32         // atoms per group (one wave-iteration)
#define GCH 32         // groups per table refill chunk (1024 atoms)
#define NB_GEMM 256    // persistent gemm grid (1 block/CU)

typedef __attribute__((ext_vector_type(8))) short short8;
typedef __attribute__((ext_vector_type(8))) unsigned short ushort8;
typedef __attribute__((ext_vector_type(4))) float f32x4;

__device__ __forceinline__ unsigned short f2bf(float f) {
  unsigned u = __float_as_uint(f);
  u = (u + 0x7FFFu + ((u >> 16) & 1u)) >> 16;   // round-to-nearest-even
  return (unsigned short)u;
}

// async global->LDS, 16B per lane; lds dest wave-uniform base (+lane*16 HW).
__device__ __forceinline__ void gload_lds16(const void* gsrc, void* ldst) {
  __builtin_amdgcn_global_load_lds(
      (const __attribute__((address_space(1))) unsigned*)gsrc,
      (__attribute__((address_space(3))) unsigned*)(uintptr_t)(unsigned)(uintptr_t)ldst,
      16, 0, 0);
}

// pack 8 fp32 -> short8 of bf16 (RNE, packed cvt)
__device__ __forceinline__ short8 cvt8(float4 lo, float4 hi) {
  union { short8 s; unsigned u[4]; } r;
  __hip_bfloat162 t;
  t = __float22bfloat162_rn(make_float2(lo.x, lo.y)); r.u[0] = *(unsigned*)&t;
  t = __float22bfloat162_rn(make_float2(lo.z, lo.w)); r.u[1] = *(unsigned*)&t;
  t = __float22bfloat162_rn(make_float2(hi.x, hi.y)); r.u[2] = *(unsigned*)&t;
  t = __float22bfloat162_rn(make_float2(hi.z, hi.w)); r.u[3] = *(unsigned*)&t;
  return r.s;
}

// ---- prep kernels -----------------------------------------------------------

// wt layout: chunk(e,step) = wt + (e*8+step)*BCHUNK bytes; within chunk,
// bf16 for (n,kk) at byte ((n*64 + kk*2) ^ ((n&7)<<4)).  Linear copy into
// LDS reproduces the swizzled layout gemm_k's ds_reads expect (rule #21).
__global__ void convw_k(const float* __restrict__ W1, unsigned short* __restrict__ wt, int NE) {
  __shared__ float ldsW[32 * 260];   // 32 k-rows x 256 n, padded
  int blk = blockIdx.x;              // e*8 + step
  int e = blk >> 3, step = blk & 7;
  int tid = threadIdx.x;
  int k0 = step * 32;
  {
    int kk = tid >> 3, part = tid & 7;
    const float* src = W1 + ((size_t)e << 16) + (size_t)(k0 + kk) * NDIM + part * 32;
    #pragma unroll
    for (int j = 0; j < 8; ++j) {
      float4 v = *(const float4*)(src + j * 4);
      *(float4*)&ldsW[kk * 260 + part * 32 + j * 4] = v;
    }
  }
  __syncthreads();
  {
    int n = tid;
    unsigned short v[32];
    #pragma unroll
    for (int kk = 0; kk < 32; ++kk) v[kk] = f2bf(ldsW[kk * 260 + n]);
    char* chunk = (char*)wt + (size_t)blk * BCHUNK;
    unsigned swz = (unsigned)((n & 7) << 4);
    #pragma unroll
    for (int g = 0; g < 4; ++g)
      *(ushort8*)(chunk + (((unsigned)(n * 64 + g * 16)) ^ swz)) = *(ushort8*)&v[g * 8];
  }
}

// per-block histogram, deterministic (ballot-based, no atomics)
__global__ void bhist_k(const int* __restrict__ sp, int n, int* __restrict__ bc, int NE) {
  __shared__ int wc[4][16];
  int tid = threadIdx.x;
  int i = blockIdx.x * 256 + tid;
  int s = (i < n) ? sp[i] : -1;
  int w = tid >> 6, lane = tid & 63;
  for (int e = 0; e < NE; ++e) {
    unsigned long long m = __ballot(s == e);
    if (lane == 0) wc[w][e] = __popcll(m);
  }
  __syncthreads();
  if (tid < NE) bc[blockIdx.x * NE + tid] = wc[0][tid] + wc[1][tid] + wc[2][tid] + wc[3][tid];
}

// deterministic scan: blockCounts -> block offsets, species atom starts,
// species GROUP offsets, and gemm block->species partition.
__global__ void scan_k(const int* __restrict__ bc, int* __restrict__ bo,
                       int* __restrict__ atom_start, int* __restrict__ goff,
                       int* __restrict__ bstart, int nblocks, int NE) {
  __shared__ int csum[256];
  __shared__ int coff[256];
  __shared__ int stot[16];
  __shared__ int sbase[16];
  int tid = threadIdx.x;
  int per = (nblocks + CHUNKS - 1) / CHUNKS;
  int e = tid / CHUNKS, c = tid % CHUNKS;
  int b0 = c * per, b1 = b0 + per; if (b1 > nblocks) b1 = nblocks;
  if (tid < NE * CHUNKS) {
    int s = 0;
    for (int b = b0; b < b1; ++b) s += bc[b * NE + e];
    csum[tid] = s;
  }
  __syncthreads();
  if (tid < NE) {
    int r = 0;
    for (int c2 = 0; c2 < CHUNKS; ++c2) { coff[tid * CHUNKS + c2] = r; r += csum[tid * CHUNKS + c2]; }
    stot[tid] = r;
  }
  __syncthreads();
  if (tid == 0) {
    int a = 0, t = 0;
    for (int e2 = 0; e2 < NE; ++e2) {
      sbase[e2] = a;
      atom_start[e2] = a; goff[e2] = t;
      a += stot[e2]; t += (stot[e2] + GRP - 1) / GRP;
    }
    atom_start[NE] = a; goff[NE] = t;
    // partition NB_GEMM blocks across species proportional to groups, >=1
    int ntl = t > 0 ? t : 1;
    int nbk[16]; int tot = 0, emax = 0;
    for (int e2 = 0; e2 < NE; ++e2) {
      int nt = goff[e2 + 1] - goff[e2];
      int v = (nt > 0) ? (int)(((long long)nt * NB_GEMM) / ntl) : 0;
      if (nt > 0 && v < 1) v = 1;
      nbk[e2] = v; tot += v;
      if (nbk[e2] > nbk[emax]) emax = e2;
    }
    nbk[emax] += NB_GEMM - tot;
    int bacc = 0;
    for (int e2 = 0; e2 < NE; ++e2) { bstart[e2] = bacc; bacc += nbk[e2]; }
    bstart[NE] = bacc;
  }
  __syncthreads();
  if (tid < NE * CHUNKS) {
    int run = sbase[e] + coff[tid];
    for (int b = b0; b < b1; ++b) { bo[b * NE + e] = run; run += bc[b * NE + e]; }
  }
}

// deterministic scatter: rank = block-offset + wave-prefix + lane-prefix
__global__ void dscatter_k(const int* __restrict__ sp, int n, const int* __restrict__ bo,
                           int* __restrict__ sorted, int NE) {
  __shared__ int wc[4][16];
  int tid = threadIdx.x;
  int i = blockIdx.x * 256 + tid;
  int s = (i < n) ? sp[i] : -1;
  int w = tid >> 6, lane = tid & 63;
  for (int e = 0; e < NE; ++e) {
    unsigned long long m = __ballot(s == e);
    if (lane == 0) wc[w][e] = __popcll(m);
  }
  __syncthreads();
  for (int e = 0; e < NE; ++e) {
    unsigned long long m = __ballot(s == e);
    if (s == e) {
      int wpre = 0;
      for (int w2 = 0; w2 < 4; ++w2) if (w2 < w) wpre += wc[w2][e];
      int rank = __popcll(m & ((1ull << lane) - 1ull));
      sorted[bo[blockIdx.x * NE + e] + wpre + rank] = i;
    }
  }
}

// ---- wave-autonomous fused grouped GEMM + SiLU + layer2 ---------------------

__global__ __launch_bounds__(512, 1) void gemm_k(
    const float* __restrict__ x, const unsigned short* __restrict__ wt,
    const float* __restrict__ b1, const float* __restrict__ w2,
    const float* __restrict__ b2, const int* __restrict__ sorted,
    const int* __restrict__ atom_start, const int* __restrict__ goff,
    const int* __restrict__ bstart, float* __restrict__ out, int NE)
{
  // LDS ~138 KB: full W1[e] bf16 (8 chunks x 16KB, swizzled image) +
  // b1/w2 slices + atom table.  1 block/CU, 8 waves, no grind barriers.
  __shared__ __align__(16) char ldsW[8 * BCHUNK];      // 128 KB
  __shared__ __align__(16) float b1s[NDIM], w2s[NDIM];
  __shared__ int ldsAtoms[GCH * GRP];                  // 1024 atoms / chunk
  __shared__ int goffs[17], astart[17], bst[17];

  int tid = threadIdx.x, lane = tid & 63, wid = tid >> 6;   // wid 0..7
  int lr = lane & 15, lg = lane >> 4;

  if (tid <= NE) {
    goffs[tid] = goff[tid]; astart[tid] = atom_start[tid]; bst[tid] = bstart[tid];
  }
  __syncthreads();

  // ---- block -> (species, group range) ----
  int b = blockIdx.x;
  int e = 0;
  while (b >= bst[e + 1]) ++e;
  int j = b - bst[e], nbe = bst[e + 1] - bst[e];
  int nge = goffs[e + 1] - goffs[e];
  int q = nge / nbe, r = nge % nbe;
  int gcnt = q + (j < r ? 1 : 0);
  if (gcnt <= 0) return;
  int g0 = j * q + (j < r ? j : r);          // group index within species
  int rs0 = astart[e] + g0 * GRP;            // first atom (global sorted idx)
  int rvAll = astart[e + 1] - rs0;           // valid atoms in this block

  // ---- W1[e] -> LDS (128 KB, linear copy of pre-swizzled image) ----
  {
    const char* wbase = (const char*)wt + (size_t)e * 8 * BCHUNK;
    #pragma unroll
    for (int i = 0; i < 16; ++i) {
      int off = (wid * 16 + i) * 1024;
      gload_lds16(wbase + off + lane * 16, ldsW + off);
    }
    if (tid < NDIM) {
      b1s[tid] = b1[(size_t)e * NDIM + tid];
      w2s[tid] = w2[(size_t)e * NDIM + tid];
    }
  }
  float b2v = b2[e];

  unsigned aoff = ((unsigned)(lr * 64 + lg * 16)) ^ ((unsigned)((lr & 7) << 4));

  // ---- grind: chunks of GCH groups (table refill); waves independent ----
  for (int gc0 = 0; gc0 < gcnt; gc0 += GCH) {
    int gce = gc0 + GCH < gcnt ? gc0 + GCH : gcnt;
    __syncthreads();   // prev chunk's readers done (covers W-load 1st iter: vmcnt drain)
    for (int i = tid; i < (gce - gc0) * GRP; i += 512) {
      int aidx = gc0 * GRP + i;
      ldsAtoms[i] = sorted[rs0 + (aidx < rvAll ? aidx : rvAll - 1)];
    }
    __syncthreads();

    for (int g = gc0 + wid; g < gce; g += 8) {
      int tb = (g - gc0) * GRP;
      int a0 = ldsAtoms[tb + lr];
      int a1 = ldsAtoms[tb + 16 + lr];
      const float* xp0 = x + (size_t)a0 * NDIM + lg * 8;
      const float* xp1 = x + (size_t)a1 * NDIM + lg * 8;

      // x fragments -> registers, converted ONCE (64 VGPRs, resident)
      short8 af0[8], af1[8];
      #pragma unroll
      for (int s = 0; s < 8; ++s) {
        float4 p0 = *(const float4*)(xp0 + s * 32);
        float4 q0 = *(const float4*)(xp0 + s * 32 + 4);
        float4 p1 = *(const float4*)(xp1 + s * 32);
        float4 q1 = *(const float4*)(xp1 + s * 32 + 4);
        af0[s] = cvt8(p0, q0);
        af1[s] = cvt8(p1, q1);
      }

      // n-pair loop: only 4 accumulators live at a time (16 VGPRs)
      float s0 = 0.f, s1 = 0.f;
      #pragma unroll
      for (int np = 0; np < 8; ++np) {
        const f32x4 zero = {0.f, 0.f, 0.f, 0.f};
        f32x4 accA0 = zero, accA1 = zero, accB0 = zero, accB1 = zero;
        const char* baseA = ldsW + np * 1024 + aoff;          // nf = np
        const char* baseB = ldsW + (np + 8) * 1024 + aoff;    // nf = np+8
        #pragma unroll
        for (int s = 0; s < 8; ++s) {
          short8 bfA = *(const short8*)(baseA + s * BCHUNK);
          short8 bfB = *(const short8*)(baseB + s * BCHUNK);
          accA0 = __builtin_amdgcn_mfma_f32_16x16x32_bf16(bfA, af0[s], accA0, 0, 0, 0);
          accA1 = __builtin_amdgcn_mfma_f32_16x16x32_bf16(bfA, af1[s], accA1, 0, 0, 0);
          accB0 = __builtin_amdgcn_mfma_f32_16x16x32_bf16(bfB, af0[s], accB0, 0, 0, 0);
          accB1 = __builtin_amdgcn_mfma_f32_16x16x32_bf16(bfB, af1[s], accB1, 0, 0, 0);
        }
        // fold into running scalars: lane holds D[n=nf*16+lg*4+rg][atom]
        f32x4 bbA = *(const f32x4*)&b1s[np * 16 + lg * 4];
        f32x4 wvA = *(const f32x4*)&w2s[np * 16 + lg * 4];
        f32x4 bbB = *(const f32x4*)&b1s[(np + 8) * 16 + lg * 4];
        f32x4 wvB = *(const f32x4*)&w2s[(np + 8) * 16 + lg * 4];
        #pragma unroll
        for (int rg = 0; rg < 4; ++rg) {
          float h;
          h = accA0[rg] + bbA[rg]; s0 += h * __builtin_amdgcn_rcpf(1.f + __expf(-h)) * wvA[rg];
          h = accA1[rg] + bbA[rg]; s1 += h * __builtin_amdgcn_rcpf(1.f + __expf(-h)) * wvA[rg];
          h = accB0[rg] + bbB[rg]; s0 += h * __builtin_amdgcn_rcpf(1.f + __expf(-h)) * wvB[rg];
          h = accB1[rg] + bbB[rg]; s1 += h * __builtin_amdgcn_rcpf(1.f + __expf(-h)) * wvB[rg];
        }
      }
      s0 += __shfl_xor(s0, 16, 64); s0 += __shfl_xor(s0, 32, 64);
      s1 += __shfl_xor(s1, 16, 64); s1 += __shfl_xor(s1, 32, 64);
      if (lg == 0)      out[a0] = s0 + b2v;
      else if (lg == 1) out[a1] = s1 + b2v;
    }
  }
}

// ---- launch -----------------------------------------------------------------

extern "C" void kernel_launch(void* const* d_in, const int* in_sizes, int n_in,
                              void* d_out, int out_size, void* d_ws, size_t ws_size,
                              hipStream_t stream) {
  const float* x  = (const float*)d_in[0];
  const int*   sp = (const int*)d_in[1];
  const float* W1 = (const float*)d_in[2];
  const float* b1 = (const float*)d_in[3];
  const float* W2 = (const float*)d_in[4];
  const float* b2 = (const float*)d_in[5];
  float* out = (float*)d_out;

  int n_atoms = in_sizes[0] / NDIM;
  int NE = in_sizes[2] / (NDIM * NDIM);
  int nblocks = (n_atoms + 255) / 256;

  // workspace layout (all 256-aligned); every word read is written this call.
  char* wsb = (char*)d_ws;
  size_t o = 0;
  int* bc = (int*)(wsb + o);         o += ((size_t)nblocks * NE * 4 + 255) & ~(size_t)255;
  int* bo = (int*)(wsb + o);         o += ((size_t)nblocks * NE * 4 + 255) & ~(size_t)255;
  int* atom_start = (int*)(wsb + o); o += 256;
  int* goff       = (int*)(wsb + o); o += 256;
  int* bstart     = (int*)(wsb + o); o += 256;
  int* sorted     = (int*)(wsb + o); o += ((size_t)n_atoms * 4 + 255) & ~(size_t)255;
  unsigned short* wt = (unsigned short*)(wsb + o);   // NE*128KB, 256-aligned

  hipLaunchKernelGGL(convw_k, dim3(NE * 8), dim3(256), 0, stream, W1, wt, NE);
  hipLaunchKernelGGL(bhist_k, dim3(nblocks), dim3(256), 0, stream, sp, n_atoms, bc, NE);
  hipLaunchKernelGGL(scan_k, dim3(1), dim3(256), 0, stream, bc, bo, atom_start, goff,
                     bstart, nblocks, NE);
  hipLaunchKernelGGL(dscatter_k, dim3(nblocks), dim3(256), 0, stream, sp, n_atoms, bo,
                     sorted, NE);

  hipLaunchKernelGGL(gemm_k, dim3(NB_GEMM), dim3(512), 0, stream,
                     x, wt, b1, W2, b2, sorted, atom_start, goff, bstart, out, NE);
}

// Round 16
// 63.414 us; speedup vs baseline: 4.6323x; 4.1348x over previous
//
#include <hip/hip_runtime.h>
#include <hip/hip_bf16.h>
#include <stdint.h>

// ElementReadoutMLP: species-routed 2-layer MLP, fused.
// r16 = r10 (best measured: 61.1us total) + NON-TEMPORAL hints on the
// zero-reuse streams (x gather loads, out stores, W1 prep reads), with the
// r15 compile fix: NT builtins need ext_vector types, not HIP float4.
//   bhist_k / scan_k / dscatter_k : countsort atoms by species;
//     scan_k also partitions gemm blocks across species (proportional, >=1).
//   convw_k : W1 -> pre-swizzled bf16 wt via LDS transpose (coalesced reads)
//   gemm_k  : PERSISTENT grouped GEMM, 256 blocks x 512 thr, ONE species per
//             block, 64-atom tiles.  A reg-staged (coalesced NT f32x4),
//             cvt once, swizzled bf16 LDS tile.  MFMA SWAPPED: D[n][atom];
//             epilogue reduce = in-lane SiLU+w2 dot + 2 shfl_xor.
//             Barriers LDS-only; next tile's A prefetch rides in VGPRs.

#define NDIM 256
#define CHUNKS 16      // scan chunks per species (NE*CHUNKS <= 256)
#define BCHUNK 16384   // bytes per B k-chunk (256 n x 32 k x 2B)
#define TROWS 64       // atoms per tile
#define MAXT 16        // max tiles per block
#define NB_GEMM 256    // persistent gemm grid

typedef __attribute__((ext_vector_type(8))) short short8;
typedef __attribute__((ext_vector_type(8))) unsigned short ushort8;
typedef __attribute__((ext_vector_type(4))) float f32x4;
typedef __attribute__((ext_vector_type(2))) unsigned u32x2;

__device__ __forceinline__ unsigned short f2bf(float f) {
  unsigned u = __float_as_uint(f);
  u = (u + 0x7FFFu + ((u >> 16) & 1u)) >> 16;   // round-to-nearest-even
  return (unsigned short)u;
}

__device__ __forceinline__ unsigned pk2(float a, float b) {
  return (unsigned)f2bf(a) | ((unsigned)f2bf(b) << 16);
}

__device__ __forceinline__ f32x4 nt_load4(const float* p) {
  return __builtin_nontemporal_load((const f32x4*)p);
}

// ---- prep kernels -----------------------------------------------------------

// wt layout: chunk(e,step) = wt + (e*8+step)*BCHUNK bytes; within chunk,
// bf16 for (n,kk) at byte ((n*64 + kk*2) ^ ((n&7)<<4)).
// One block per (e,step): coalesced NT read of 32 k-rows into LDS, transpose,
// swizzled write.
__global__ void convw_k(const float* __restrict__ W1, unsigned short* __restrict__ wt, int NE) {
  __shared__ float ldsW[32 * 260];   // 32 k-rows x 256 n, pad 260 (bank spread)
  int blk = blockIdx.x;              // e*8 + step
  int e = blk >> 3, step = blk & 7;
  int tid = threadIdx.x;
  int k0 = step * 32;
  {
    int kk = tid >> 3, part = tid & 7;   // 8 threads cover one 1KB k-row
    const float* src = W1 + ((size_t)e << 16) + (size_t)(k0 + kk) * NDIM + part * 32;
    #pragma unroll
    for (int j = 0; j < 8; ++j) {
      f32x4 v = nt_load4(src + j * 4);
      *(f32x4*)&ldsW[kk * 260 + part * 32 + j * 4] = v;
    }
  }
  __syncthreads();
  {
    int n = tid;
    unsigned short v[32];
    #pragma unroll
    for (int kk = 0; kk < 32; ++kk) v[kk] = f2bf(ldsW[kk * 260 + n]);
    char* chunk = (char*)wt + (size_t)blk * BCHUNK;
    unsigned swz = (unsigned)((n & 7) << 4);
    #pragma unroll
    for (int g = 0; g < 4; ++g)
      *(ushort8*)(chunk + (((unsigned)(n * 64 + g * 16)) ^ swz)) = *(ushort8*)&v[g * 8];
  }
}

// per-block histogram, deterministic (ballot-based, no atomics)
__global__ void bhist_k(const int* __restrict__ sp, int n, int* __restrict__ bc, int NE) {
  __shared__ int wc[4][16];
  int tid = threadIdx.x;
  int i = blockIdx.x * 256 + tid;
  int s = (i < n) ? sp[i] : -1;
  int w = tid >> 6, lane = tid & 63;
  for (int e = 0; e < NE; ++e) {
    unsigned long long m = __ballot(s == e);
    if (lane == 0) wc[w][e] = __popcll(m);
  }
  __syncthreads();
  if (tid < NE) bc[blockIdx.x * NE + tid] = wc[0][tid] + wc[1][tid] + wc[2][tid] + wc[3][tid];
}

// deterministic scan: blockCounts -> block offsets, species starts, tile
// offsets, and gemm block->species partition.
__global__ void scan_k(const int* __restrict__ bc, int* __restrict__ bo,
                       int* __restrict__ atom_start, int* __restrict__ tile_off,
                       int* __restrict__ bstart, int nblocks, int NE) {
  __shared__ int csum[256];
  __shared__ int coff[256];
  __shared__ int stot[16];
  __shared__ int sbase[16];
  int tid = threadIdx.x;
  int per = (nblocks + CHUNKS - 1) / CHUNKS;
  int e = tid / CHUNKS, c = tid % CHUNKS;
  int b0 = c * per, b1 = b0 + per; if (b1 > nblocks) b1 = nblocks;
  if (tid < NE * CHUNKS) {
    int s = 0;
    for (int b = b0; b < b1; ++b) s += bc[b * NE + e];
    csum[tid] = s;
  }
  __syncthreads();
  if (tid < NE) {
    int r = 0;
    for (int c2 = 0; c2 < CHUNKS; ++c2) { coff[tid * CHUNKS + c2] = r; r += csum[tid * CHUNKS + c2]; }
    stot[tid] = r;
  }
  __syncthreads();
  if (tid == 0) {
    int a = 0, t = 0;
    for (int e2 = 0; e2 < NE; ++e2) {
      sbase[e2] = a;
      atom_start[e2] = a; tile_off[e2] = t;
      a += stot[e2]; t += (stot[e2] + TROWS - 1) / TROWS;
    }
    atom_start[NE] = a; tile_off[NE] = t;
    // ---- partition NB_GEMM blocks across species, proportional, >=1 ----
    int ntl = t > 0 ? t : 1;
    int nbk[16]; int tot = 0, emax = 0;
    for (int e2 = 0; e2 < NE; ++e2) {
      int nt = tile_off[e2 + 1] - tile_off[e2];
      int v = (nt > 0) ? (int)(((long long)nt * NB_GEMM) / ntl) : 0;
      if (nt > 0 && v < 1) v = 1;
      nbk[e2] = v; tot += v;
      if (nbk[e2] > nbk[emax]) emax = e2;
    }
    nbk[emax] += NB_GEMM - tot;
    int bacc = 0;
    for (int e2 = 0; e2 < NE; ++e2) { bstart[e2] = bacc; bacc += nbk[e2]; }
    bstart[NE] = bacc;
  }
  __syncthreads();
  if (tid < NE * CHUNKS) {
    int run = sbase[e] + coff[tid];
    for (int b = b0; b < b1; ++b) { bo[b * NE + e] = run; run += bc[b * NE + e]; }
  }
}

// deterministic scatter: rank = block-offset + wave-prefix + lane-prefix
__global__ void dscatter_k(const int* __restrict__ sp, int n, const int* __restrict__ bo,
                           int* __restrict__ sorted, int NE) {
  __shared__ int wc[4][16];
  int tid = threadIdx.x;
  int i = blockIdx.x * 256 + tid;
  int s = (i < n) ? sp[i] : -1;
  int w = tid >> 6, lane = tid & 63;
  for (int e = 0; e < NE; ++e) {
    unsigned long long m = __ballot(s == e);
    if (lane == 0) wc[w][e] = __popcll(m);
  }
  __syncthreads();
  for (int e = 0; e < NE; ++e) {
    unsigned long long m = __ballot(s == e);
    if (s == e) {
      int wpre = 0;
      for (int w2 = 0; w2 < 4; ++w2) if (w2 < w) wpre += wc[w2][e];
      int rank = __popcll(m & ((1ull << lane) - 1ull));
      sorted[bo[blockIdx.x * NE + e] + wpre + rank] = i;
    }
  }
}

// ---- persistent fused grouped GEMM + SiLU + layer2 --------------------------

__global__ __launch_bounds__(512, 1) void gemm_k(
    const float* __restrict__ x, const unsigned short* __restrict__ wt,
    const float* __restrict__ b1, const float* __restrict__ w2,
    const float* __restrict__ b2, const int* __restrict__ sorted,
    const int* __restrict__ atom_start, const int* __restrict__ tile_off,
    const int* __restrict__ bstart, float* __restrict__ out, int NE)
{
  // LDS ~39 KB: bf16 A tile (64 x 512B, XOR-swizzled) + partials + atoms.
  __shared__ __align__(16) char ldsT[TROWS * 512];
  __shared__ float partLds[8 * TROWS];      // 8 waves x 64 atoms
  __shared__ int ldsAtoms[MAXT * TROWS];
  __shared__ int toffs[17], astart[17], bst[17];

  int tid = threadIdx.x, lane = tid & 63, wid = tid >> 6;   // wid 0..7
  int lr = lane & 15, lg = lane >> 4;

  if (tid <= NE) {
    toffs[tid] = tile_off[tid]; astart[tid] = atom_start[tid]; bst[tid] = bstart[tid];
  }
  __syncthreads();

  // ---- block -> (species, tile range); ONE species per block ----
  int b = blockIdx.x;
  int e = 0;
  while (b >= bst[e + 1]) ++e;
  int j = b - bst[e], nbe = bst[e + 1] - bst[e];
  int nte = toffs[e + 1] - toffs[e];
  int q = nte / nbe, r = nte % nbe;
  int cnt = q + (j < r ? 1 : 0);
  if (cnt <= 0) return;
  if (cnt > MAXT) cnt = MAXT;   // unreachable at these sizes
  int t0 = toffs[e] + j * q + (j < r ? j : r);
  int t1 = t0 + cnt;

  // ---- cache atom indices in LDS (clamped -> benign duplicate writes) ----
  {
    int rs0 = astart[e] + (t0 - toffs[e]) * TROWS;
    int rvAll = astart[e + 1] - rs0;
    for (int i = tid; i < cnt * TROWS; i += 512) {
      int rloc = (i < rvAll) ? i : (rvAll - 1);
      ldsAtoms[i] = sorted[rs0 + rloc];
    }
  }
  __syncthreads();

  // ---- B slice + layer params, loaded ONCE (L2-hot: NT x-loads keep L2
  // clean for W/B lines) ----
  short8 bf[2][8];
  float bbv[2][4], wvv[2][4];
  {
    const char* wbase = (const char*)wt + (size_t)e * 8 * BCHUNK;
    #pragma unroll
    for (int mf = 0; mf < 2; ++mf) {
      int ncol = wid * 32 + mf * 16 + lr;
      unsigned off = ((unsigned)(ncol * 64 + lg * 16)) ^ ((unsigned)((ncol & 7) << 4));
      #pragma unroll
      for (int s = 0; s < 8; ++s)
        bf[mf][s] = *(const short8*)(wbase + (size_t)s * BCHUNK + off);
      #pragma unroll
      for (int rg = 0; rg < 4; ++rg) {
        int n = wid * 32 + mf * 16 + lg * 4 + rg;   // swapped-layout n per lane
        bbv[mf][rg] = b1[(size_t)e * NDIM + n];
        wvv[mf][rg] = w2[(size_t)e * NDIM + n];
      }
    }
  }
  float b2v = b2[e];
  #pragma unroll
  for (int mf = 0; mf < 2; ++mf)
    #pragma unroll
    for (int s = 0; s < 8; ++s) asm volatile("" : "+v"(bf[mf][s]));

  // ---- A staging map: 8 threads per 1KB row, 8 f32x4 each, coalesced NT ----
  int srow = tid >> 3;          // 0..63
  int skc  = tid & 7;
  unsigned swzW = (unsigned)((srow & 7) << 4);
  f32x4 xr[8];
  {
    int atom = ldsAtoms[srow];
    const float* xp = x + (size_t)atom * NDIM + skc * 4;
    #pragma unroll
    for (int jj = 0; jj < 8; ++jj) xr[jj] = nt_load4(xp + jj * 32);
  }

  for (int t = t0; t < t1; ++t) {
    // ---- cvt once + write swizzled bf16 tile (k elems j*32+skc*4..+3) ----
    #pragma unroll
    for (int jj = 0; jj < 8; ++jj) {
      u32x2 w;
      w[0] = pk2(xr[jj][0], xr[jj][1]); w[1] = pk2(xr[jj][2], xr[jj][3]);
      *(u32x2*)(ldsT + (((unsigned)(srow * 512 + jj * 64 + skc * 8)) ^ swzW)) = w;
    }
    // ---- prefetch next tile's A into regs (hides under compute) ----
    if (t + 1 < t1) {
      int atom = ldsAtoms[(t + 1 - t0) * TROWS + srow];
      const float* xp = x + (size_t)atom * NDIM + skc * 4;
      #pragma unroll
      for (int jj = 0; jj < 8; ++jj) xr[jj] = nt_load4(xp + jj * 32);
    }

    asm volatile("s_waitcnt lgkmcnt(0)" ::: "memory");
    __builtin_amdgcn_s_barrier();
    __builtin_amdgcn_sched_barrier(0);

    // ---- compute: SWAPPED mfma -> acc[mf][nf] = D[n][atom] ----
    f32x4 acc[2][4];
    const f32x4 zero = {0.f, 0.f, 0.f, 0.f};
    #pragma unroll
    for (int i = 0; i < 2; ++i)
      #pragma unroll
      for (int jj = 0; jj < 4; ++jj) acc[i][jj] = zero;

    #pragma unroll
    for (int step = 0; step < 8; ++step) {
      short8 af[4];
      #pragma unroll
      for (int nf = 0; nf < 4; ++nf) {
        unsigned off = ((unsigned)((nf * 16 + lr) * 512 + step * 64 + lg * 16))
                     ^ ((unsigned)((lr & 7) << 4));
        af[nf] = *(const short8*)(ldsT + off);
      }
      #pragma unroll
      for (int mf = 0; mf < 2; ++mf)
        #pragma unroll
        for (int nf = 0; nf < 4; ++nf)
          acc[mf][nf] = __builtin_amdgcn_mfma_f32_16x16x32_bf16(bf[mf][step], af[nf], acc[mf][nf], 0, 0, 0);
    }

    // ---- epilogue: lane holds D[n = wid*32+mf*16+lg*4+rg][atom = nf*16+lr].
    // SiLU+w2-dot in-lane over (mf,rg); cross-lane reduce = 2 shfl_xor. ----
    float p[4];
    #pragma unroll
    for (int nf = 0; nf < 4; ++nf) {
      float s = 0.f;
      #pragma unroll
      for (int mf = 0; mf < 2; ++mf)
        #pragma unroll
        for (int rg = 0; rg < 4; ++rg) {
          float h = acc[mf][nf][rg] + bbv[mf][rg];
          s += h * __builtin_amdgcn_rcpf(1.f + __expf(-h)) * wvv[mf][rg];
        }
      s += __shfl_xor(s, 16, 64);
      s += __shfl_xor(s, 32, 64);
      p[nf] = s;
    }
    if (lg == 0) {
      #pragma unroll
      for (int nf = 0; nf < 4; ++nf)
        partLds[wid * TROWS + nf * 16 + lr] = p[nf];
    }

    asm volatile("s_waitcnt lgkmcnt(0)" ::: "memory");
    __builtin_amdgcn_s_barrier();
    __builtin_amdgcn_sched_barrier(0);

    if (tid < TROWS) {
      float s = b2v;
      #pragma unroll
      for (int w = 0; w < 8; ++w) s += partLds[w * TROWS + tid];
      __builtin_nontemporal_store(s, &out[ldsAtoms[(t - t0) * TROWS + tid]]);
    }
  }
}

// ---- launch -----------------------------------------------------------------

extern "C" void kernel_launch(void* const* d_in, const int* in_sizes, int n_in,
                              void* d_out, int out_size, void* d_ws, size_t ws_size,
                              hipStream_t stream) {
  const float* x  = (const float*)d_in[0];
  const int*   sp = (const int*)d_in[1];
  const float* W1 = (const float*)d_in[2];
  const float* b1 = (const float*)d_in[3];
  const float* W2 = (const float*)d_in[4];
  const float* b2 = (const float*)d_in[5];
  float* out = (float*)d_out;

  int n_atoms = in_sizes[0] / NDIM;
  int NE = in_sizes[2] / (NDIM * NDIM);
  int nblocks = (n_atoms + 255) / 256;

  // workspace layout (all 256-aligned); every word read is written this call.
  char* wsb = (char*)d_ws;
  size_t o = 0;
  int* bc = (int*)(wsb + o);         o += ((size_t)nblocks * NE * 4 + 255) & ~(size_t)255;
  int* bo = (int*)(wsb + o);         o += ((size_t)nblocks * NE * 4 + 255) & ~(size_t)255;
  int* atom_start = (int*)(wsb + o); o += 256;
  int* tile_off   = (int*)(wsb + o); o += 256;
  int* bstart     = (int*)(wsb + o); o += 256;
  int* sorted     = (int*)(wsb + o); o += ((size_t)n_atoms * 4 + 255) & ~(size_t)255;
  unsigned short* wt = (unsigned short*)(wsb + o);   // NE*128KB, 256-aligned

  hipLaunchKernelGGL(convw_k, dim3(NE * 8), dim3(256), 0, stream, W1, wt, NE);
  hipLaunchKernelGGL(bhist_k, dim3(nblocks), dim3(256), 0, stream, sp, n_atoms, bc, NE);
  hipLaunchKernelGGL(scan_k, dim3(1), dim3(256), 0, stream, bc, bo, atom_start, tile_off,
                     bstart, nblocks, NE);
  hipLaunchKernelGGL(dscatter_k, dim3(nblocks), dim3(256), 0, stream, sp, n_atoms, bo,
                     sorted, NE);

  hipLaunchKernelGGL(gemm_k, dim3(NB_GEMM), dim3(512), 0, stream,
                     x, wt, b1, W2, b2, sorted, atom_start, tile_off, bstart, out, NE);
}